// Round 9
// baseline (548.361 us; speedup 1.0000x reference)
//
#include <hip/hip_runtime.h>

#define NTOT 262144
#define BN   32
#define NT   256
#define SXS  296     // sX row stride in shorts (288 + 8 pad; conflict-free b128 reads)

typedef __attribute__((ext_vector_type(8))) short bf16x8;
typedef __attribute__((ext_vector_type(4))) float f32x4;

static __device__ __forceinline__ unsigned short f2b(float x) {
    union { float f; unsigned u; } c; c.f = x;
    unsigned r = c.u + 0x7FFFu + ((c.u >> 16) & 1u);   // RNE
    return (unsigned short)(r >> 16);
}
static __device__ __forceinline__ float b2f(unsigned short h) {
    union { unsigned u; float f; } c; c.u = ((unsigned)h) << 16; return c.f;
}
static __device__ __forceinline__ bf16x8 cvt8(const float* p) {
    float4 x = *(const float4*)p, y = *(const float4*)(p + 4);
    bf16x8 r;
    r[0] = (short)f2b(x.x); r[1] = (short)f2b(x.y); r[2] = (short)f2b(x.z); r[3] = (short)f2b(x.w);
    r[4] = (short)f2b(y.x); r[5] = (short)f2b(y.y); r[6] = (short)f2b(y.z); r[7] = (short)f2b(y.w);
    return r;
}
static __device__ __forceinline__ void glds16(const unsigned short* g, void* l) {
    __builtin_amdgcn_global_load_lds(
        (const __attribute__((address_space(1))) void*)g,
        (__attribute__((address_space(3))) void*)l, 16, 0, 0);
}

// Pack W_m_w -> bf16, 18 half-chunks [128 cols][32 k] (it = ks*2 + ch), with the
// r2-proven XOR swizzle on the k index (kk ^= ((ol>>1)&3)<<3): B-frag b128 reads
// then have each 8-lane group covering all 32 banks once (conflict-free).
// W_g_w -> bf16 k-chunked (read direct from global in gate GEMM).
__global__ void pack_w(const float* __restrict__ Wmw, const float* __restrict__ Wgw,
                       unsigned short* __restrict__ wp) {
    int t = blockIdx.x * 256 + threadIdx.x;
    if (t < 73728) {
        int o = t / 288, k = t % 288;
        int ks = k >> 5, kk = k & 31, ch = o >> 7, ol = o & 127;
        int kks = kk ^ (((ol >> 1) & 3) << 3);
        wp[(ks * 2 + ch) * 4096 + ol * 32 + kks] = f2b(Wmw[t]);
    } else if (t < 81920) {
        int j = t - 73728;
        int o = j >> 8, k = j & 255;
        wp[73728 + (k >> 5) * 1024 + o * 32 + (k & 31)] = f2b(Wgw[j]);
    }
}

// K-loop is BARRIER-FREE: W slices are wave-private (wave w stages and reads only
// cols [w*32, w*32+32) of each half-chunk), sX is read-only during the loop.
// Counted per-wave vmcnt (T4): steady-state vmcnt(2) keeps the next chunk's 2
// glds in flight; vmcnt(0) only at the last iteration. lgkmcnt(0)+sched_barrier
// before each overwrite-glds guarantees the dbuf slot's reads retired.
template<int USE_WS>
__global__ __launch_bounds__(NT, 2)
void gvp_main(const float* __restrict__ s, const float* __restrict__ V,
              const float* __restrict__ Wh, const float* __restrict__ Wmu,
              const float* __restrict__ Wmw, const float* __restrict__ Wmb,
              const float* __restrict__ Wgw, const float* __restrict__ Wgb,
              const unsigned short* __restrict__ wpack,
              float* __restrict__ out)
{
    // LDS 47,616 B -> 3 blocks/CU:
    //   sX  bf16 [32][296] 18944 B: s | s_h -> sigmoid(s_m) | gate -> V_dash f32 scratch
    //   sWb 2 x 4096 shorts 16384 B: W dbuf -> relu f32 [16][256] -> V_dash... (sc)
    //   sV  f32 [32][96] 12288 B: V tile -> V_h
    __shared__ __attribute__((aligned(16))) unsigned short sX[BN * SXS];
    __shared__ __attribute__((aligned(16))) unsigned short sWb[2 * 4096];
    __shared__ __attribute__((aligned(16))) float sV[BN * 96];

    const int t  = threadIdx.x;
    const int w  = t >> 6, l = t & 63;
    const int fr = l & 15, fq = l >> 4;
    const int n0 = blockIdx.x * BN;

    // ---------------- stage s -> sX (bf16), V -> sV; prologue W c0,c1 ----------
    #pragma unroll
    for (int i = 0; i < 8; ++i) {
        int n = i * 4 + w;
        float4 x4 = *(const float4*)&s[(size_t)(n0 + n) * 256 + 4 * l];
        ushort4 h4; h4.x = f2b(x4.x); h4.y = f2b(x4.y); h4.z = f2b(x4.z); h4.w = f2b(x4.w);
        *(ushort4*)&sX[n * SXS + 4 * l] = h4;
    }
    #pragma unroll
    for (int i = 0; i < 3; ++i) {
        int f = i * NT + t;
        *(float4*)&sV[f * 4] = *(const float4*)&V[(size_t)n0 * 96 + f * 4];
    }
    if (USE_WS) {
        #pragma unroll
        for (int c = 0; c < 2; ++c) {
            const unsigned short* src = wpack + c * 4096 + w * 1024 + l * 8;
            unsigned short* dst = sWb + c * 4096 + w * 1024;
            glds16(src, dst);
            glds16(src + 512, dst + 512);
        }
    } else {
        #pragma unroll
        for (int c = 0; c < 2; ++c) {       // it=c: ks=0, ch=c
            int ol = w * 32 + (l >> 1), kh = l & 1, x = (ol >> 1) & 3;
            const float* p = &Wmw[(c * 128 + ol) * 288 + kh * 16];
            unsigned short* dst = sWb + c * 4096;
            *(bf16x8*)&dst[ol * 32 + (((kh * 2 + 0) ^ x) << 3)] = cvt8(p);
            *(bf16x8*)&dst[ol * 32 + (((kh * 2 + 1) ^ x) << 3)] = cvt8(p + 8);
        }
    }
    __syncthreads();   // staging visible; compiler's vmcnt(0) drains c0,c1 (wanted)

    // ---------------- phase A: V_h = Wh@V (f32, Wh L1), s_h -> sX[.,256..] -----
    float vh[4][3];
    #pragma unroll
    for (int i = 0; i < 4; ++i) {
        int p = i * NT + t;
        int n = p >> 5, h = p & 31;
        const float4* vt4 = (const float4*)&sV[n * 96];
        const float4* wh4 = (const float4*)&Wh[h * 32];
        float a0 = 0.f, a1 = 0.f, a2 = 0.f;
        #pragma unroll
        for (int v4 = 0; v4 < 8; ++v4) {
            float4 wv = wh4[v4];
            float4 p0 = vt4[v4 * 3 + 0], p1 = vt4[v4 * 3 + 1], p2 = vt4[v4 * 3 + 2];
            a0 = fmaf(wv.x, p0.x, a0); a1 = fmaf(wv.x, p0.y, a1); a2 = fmaf(wv.x, p0.z, a2);
            a0 = fmaf(wv.y, p0.w, a0); a1 = fmaf(wv.y, p1.x, a1); a2 = fmaf(wv.y, p1.y, a2);
            a0 = fmaf(wv.z, p1.z, a0); a1 = fmaf(wv.z, p1.w, a1); a2 = fmaf(wv.z, p2.x, a2);
            a0 = fmaf(wv.w, p2.y, a0); a1 = fmaf(wv.w, p2.z, a1); a2 = fmaf(wv.w, p2.w, a2);
        }
        vh[i][0] = a0; vh[i][1] = a1; vh[i][2] = a2;
        float nrm = sqrtf(fmaf(a0, a0, fmaf(a1, a1, a2 * a2)));
        sX[n * SXS + 256 + h] = f2b(fmaxf(nrm, 1e-4f));
    }
    __syncthreads();            // V-tile reads done; s_h visible to all waves
    #pragma unroll
    for (int i = 0; i < 4; ++i) {
        int p = i * NT + t;
        int n = p >> 5, h = p & 31;
        sV[n * 96 + h * 3 + 0] = vh[i][0];
        sV[n * 96 + h * 3 + 1] = vh[i][1];
        sV[n * 96 + h * 3 + 2] = vh[i][2];
    }

    // ---------------- main GEMM: 18 iters, ZERO barriers, counted vmcnt --------
    f32x4 acc[2][4];
    #pragma unroll
    for (int mt = 0; mt < 2; ++mt)
        #pragma unroll
        for (int j = 0; j < 4; ++j) acc[mt][j] = (f32x4){0.f, 0.f, 0.f, 0.f};

    const int ol0 = w * 32 + fr, ol1 = ol0 + 16;
    const int bo0 = ol0 * 32 + ((fq ^ ((ol0 >> 1) & 3)) << 3);
    const int bo1 = ol1 * 32 + ((fq ^ ((ol1 >> 1) & 3)) << 3);

    #pragma unroll
    for (int it = 0; it < 18; ++it) {
        if (it >= 2) {          // wait for chunk it (per-wave FIFO: 2 loads/chunk)
            if (it <= 16) asm volatile("s_waitcnt vmcnt(2)" ::: "memory");
            else          asm volatile("s_waitcnt vmcnt(0)" ::: "memory");
            __builtin_amdgcn_sched_barrier(0);
        }
        const int ks = it >> 1;
        const unsigned short* bw = sWb + (it & 1) * 4096;
        bf16x8 a0 = *(const bf16x8*)&sX[fr * SXS + ks * 32 + fq * 8];
        bf16x8 a1 = *(const bf16x8*)&sX[(16 + fr) * SXS + ks * 32 + fq * 8];
        bf16x8 b0 = *(const bf16x8*)&bw[bo0];
        bf16x8 b1 = *(const bf16x8*)&bw[bo1];
        if (it < 16) {          // refill this dbuf slot with chunk it+2
            asm volatile("s_waitcnt lgkmcnt(0)" ::: "memory");   // slot reads retired
            __builtin_amdgcn_sched_barrier(0);
            if (USE_WS) {
                const unsigned short* src = wpack + (it + 2) * 4096 + w * 1024 + l * 8;
                unsigned short* dst = sWb + (it & 1) * 4096 + w * 1024;
                glds16(src, dst);
                glds16(src + 512, dst + 512);
            } else {
                int it2 = it + 2, ks2 = it2 >> 1, ch2 = it2 & 1;
                int ol = w * 32 + (l >> 1), kh = l & 1, x = (ol >> 1) & 3;
                const float* p = &Wmw[(ch2 * 128 + ol) * 288 + ks2 * 32 + kh * 16];
                unsigned short* dst = sWb + (it & 1) * 4096;
                *(bf16x8*)&dst[ol * 32 + (((kh * 2 + 0) ^ x) << 3)] = cvt8(p);
                *(bf16x8*)&dst[ol * 32 + (((kh * 2 + 1) ^ x) << 3)] = cvt8(p + 8);
            }
        }
        const int ji = (it & 1) * 2;
        acc[0][ji + 0] = __builtin_amdgcn_mfma_f32_16x16x32_bf16(a0, b0, acc[0][ji + 0], 0, 0, 0);
        acc[1][ji + 0] = __builtin_amdgcn_mfma_f32_16x16x32_bf16(a1, b0, acc[1][ji + 0], 0, 0, 0);
        acc[0][ji + 1] = __builtin_amdgcn_mfma_f32_16x16x32_bf16(a0, b1, acc[0][ji + 1], 0, 0, 0);
        acc[1][ji + 1] = __builtin_amdgcn_mfma_f32_16x16x32_bf16(a1, b1, acc[1][ji + 1], 0, 0, 0);
    }
    __syncthreads();            // all A-frag reads done -> sX writable

    // ---------------- epilogue: sigmoid -> sX; relu restaged via sWb -----------
    float bias[4];
    #pragma unroll
    for (int ji = 0; ji < 4; ++ji)
        bias[ji] = Wmb[(ji >> 1) * 128 + w * 32 + (ji & 1) * 16 + fr];

    float* sRel = (float*)sWb;  // [16][256] f32 per pass (16384 B = sWb exactly)
    #pragma unroll
    for (int mt = 0; mt < 2; ++mt) {
        #pragma unroll
        for (int r = 0; r < 4; ++r) {
            int row  = fq * 4 + r;
            int node = mt * 16 + row;
            #pragma unroll
            for (int ji = 0; ji < 4; ++ji) {
                int col = (ji >> 1) * 128 + w * 32 + (ji & 1) * 16 + fr;
                float m = acc[mt][ji][r] + bias[ji];
                sX[node * SXS + col] = f2b(1.f / (1.f + __expf(-m)));
                sRel[row * 256 + col] = fmaxf(m, 0.f);
            }
        }
        __syncthreads();
        #pragma unroll
        for (int i = 0; i < 4; ++i) {
            int flat = i * NT + t;            // 1024 f4 slots = 16 rows x 64
            int row = flat >> 6, c4 = flat & 63;
            float4 v4 = *(const float4*)&sRel[row * 256 + c4 * 4];
            *(float4*)&out[(size_t)(n0 + mt * 16 + row) * 256 + c4 * 4] = v4;
        }
        __syncthreads();
    }

    // ---------------- gate GEMM (B direct from global); gate bf16 -> sX[.,256..]
    {
        const int gmt = w & 1, gnt = w >> 1;
        f32x4 g = (f32x4){0.f, 0.f, 0.f, 0.f};
        #pragma unroll
        for (int ks = 0; ks < 8; ++ks) {
            bf16x8 a = *(const bf16x8*)&sX[(gmt * 16 + fr) * SXS + ks * 32 + fq * 8];
            bf16x8 b;
            if (USE_WS) b = *(const bf16x8*)&wpack[73728 + ks * 1024 + (gnt * 16 + fr) * 32 + fq * 8];
            else        b = cvt8(&Wgw[(gnt * 16 + fr) * 256 + ks * 32 + fq * 8]);
            g = __builtin_amdgcn_mfma_f32_16x16x32_bf16(a, b, g, 0, 0, 0);
        }
        int mo = gnt * 16 + fr;
        float gb = Wgb[mo];
        #pragma unroll
        for (int r = 0; r < 4; ++r) {
            int node = gmt * 16 + fq * 4 + r;
            sX[node * SXS + 256 + mo] = f2b(1.f / (1.f + __expf(-(g[r] + gb))));
        }
    }
    __syncthreads();            // gate visible; sWb dead -> f32 V_dash scratch

    // ---------------- phase D: V_mu = Wmu@V_h (f32); gate; coalesced store -----
    float* sc = (float*)sWb;    // [32][96] f32 = 12288 B
    #pragma unroll
    for (int i = 0; i < 4; ++i) {
        int p = i * NT + t;
        int n = p >> 5, m = p & 31;
        const float4* vt4 = (const float4*)&sV[n * 96];
        const float4* wm4 = (const float4*)&Wmu[m * 32];
        float a0 = 0.f, a1 = 0.f, a2 = 0.f;
        #pragma unroll
        for (int v4 = 0; v4 < 8; ++v4) {
            float4 wv = wm4[v4];
            float4 p0 = vt4[v4 * 3 + 0], p1 = vt4[v4 * 3 + 1], p2 = vt4[v4 * 3 + 2];
            a0 = fmaf(wv.x, p0.x, a0); a1 = fmaf(wv.x, p0.y, a1); a2 = fmaf(wv.x, p0.z, a2);
            a0 = fmaf(wv.y, p0.w, a0); a1 = fmaf(wv.y, p1.x, a1); a2 = fmaf(wv.y, p1.y, a2);
            a0 = fmaf(wv.z, p1.z, a0); a1 = fmaf(wv.z, p1.w, a1); a2 = fmaf(wv.z, p2.x, a2);
            a0 = fmaf(wv.w, p2.y, a0); a1 = fmaf(wv.w, p2.z, a1); a2 = fmaf(wv.w, p2.w, a2);
        }
        float g = b2f(sX[n * SXS + 256 + m]);
        sc[n * 96 + m * 3 + 0] = g * a0;
        sc[n * 96 + m * 3 + 1] = g * a1;
        sc[n * 96 + m * 3 + 2] = g * a2;
    }
    __syncthreads();
    const size_t VBASE = (size_t)NTOT * 256;
    #pragma unroll
    for (int i = 0; i < 3; ++i) {
        int f = i * NT + t;
        *(float4*)&out[VBASE + (size_t)n0 * 96 + f * 4] = *(const float4*)&sc[f * 4];
    }
}

extern "C" void kernel_launch(void* const* d_in, const int* in_sizes, int n_in,
                              void* d_out, int out_size, void* d_ws, size_t ws_size,
                              hipStream_t stream) {
    const float* s   = (const float*)d_in[0];
    const float* V   = (const float*)d_in[1];
    const float* Wh  = (const float*)d_in[2];
    const float* Wmu = (const float*)d_in[3];
    const float* Wmw = (const float*)d_in[4];
    const float* Wmb = (const float*)d_in[5];
    const float* Wgw = (const float*)d_in[6];
    const float* Wgb = (const float*)d_in[7];
    float* out = (float*)d_out;

    dim3 grid(NTOT / BN);   // 8192
    dim3 block(NT);         // 256

    if (ws_size >= 163840) {
        pack_w<<<320, 256, 0, stream>>>(Wmw, Wgw, (unsigned short*)d_ws);
        gvp_main<1><<<grid, block, 0, stream>>>(s, V, Wh, Wmu, Wmw, Wmb, Wgw, Wgb,
                                                (const unsigned short*)d_ws, out);
    } else {
        gvp_main<0><<<grid, block, 0, stream>>>(s, V, Wh, Wmu, Wmw, Wmb, Wgw, Wgb,
                                                nullptr, out);
    }
}

// Round 10
// 251.820 us; speedup vs baseline: 2.1776x; 2.1776x over previous
//
#include <hip/hip_runtime.h>

#define NTOT 262144
#define BN   32
#define NT   256
#define SXS  296     // sX row stride in shorts (288 + 8 pad; conflict-free b128 reads)
#define VTS  36      // V^T / V_h^T row stride in shorts (32 + 4 pad; 16 distinct banks)

typedef __attribute__((ext_vector_type(8))) short bf16x8;
typedef __attribute__((ext_vector_type(4))) float f32x4;

static __device__ __forceinline__ unsigned short f2b(float x) {
    union { float f; unsigned u; } c; c.f = x;
    unsigned r = c.u + 0x7FFFu + ((c.u >> 16) & 1u);   // RNE
    return (unsigned short)(r >> 16);
}
static __device__ __forceinline__ float b2f(unsigned short h) {
    union { unsigned u; float f; } c; c.u = ((unsigned)h) << 16; return c.f;
}
static __device__ __forceinline__ bf16x8 cvt8(const float* p) {
    float4 x = *(const float4*)p, y = *(const float4*)(p + 4);
    bf16x8 r;
    r[0] = (short)f2b(x.x); r[1] = (short)f2b(x.y); r[2] = (short)f2b(x.z); r[3] = (short)f2b(x.w);
    r[4] = (short)f2b(y.x); r[5] = (short)f2b(y.y); r[6] = (short)f2b(y.z); r[7] = (short)f2b(y.w);
    return r;
}
static __device__ __forceinline__ void glds16(const unsigned short* g, void* l) {
    __builtin_amdgcn_global_load_lds(
        (const __attribute__((address_space(1))) void*)g,
        (__attribute__((address_space(3))) void*)l, 16, 0, 0);
}

// r2-proven pack: W_m_w -> bf16, 9 full chunks [256 out][32 k], XOR-swizzled on k
// (kk ^= ((o>>1)&3)<<3) so B-frag ds_read_b128 spreads across all banks.
// W_g_w -> bf16 k-chunked at offset 73728.
__global__ void pack_w(const float* __restrict__ Wmw, const float* __restrict__ Wgw,
                       unsigned short* __restrict__ wp) {
    int t = blockIdx.x * 256 + threadIdx.x;
    if (t < 73728) {
        int o = t / 288, k = t % 288;
        int kks = (k & 31) ^ (((o >> 1) & 3) << 3);
        wp[(k >> 5) * 8192 + o * 32 + kks] = f2b(Wmw[t]);
    } else if (t < 81920) {
        int j = t - 73728;
        int o = j >> 8, k = j & 255;
        wp[73728 + (k >> 5) * 1024 + o * 32 + (k & 31)] = f2b(Wgw[j]);
    }
}

// Phases A (V_h = Wh@V, s_h) and D (V_mu = Wmu@V_h) are MFMA with c-major rows
// (row = c*32+n, M=96, K=32, N=32): each wave does 3 MFMAs (c=0,1,2) with the
// SAME (node, h/m) lane mapping across c -> norm/gate are lane-local.
template<int USE_WS>
__global__ __launch_bounds__(NT, 2)
void gvp_main(const float* __restrict__ s, const float* __restrict__ V,
              const float* __restrict__ Wh, const float* __restrict__ Wmu,
              const float* __restrict__ Wmw, const float* __restrict__ Wmb,
              const float* __restrict__ Wgw, const float* __restrict__ Wgb,
              const unsigned short* __restrict__ wpack,
              float* __restrict__ out)
{
    // LDS 58,624 B -> 2 blocks/CU:
    //   sX   bf16 [32][296] 18944 B: s | s_h -> sigmoid(s_m) | gate
    //   sWb  2 x 8192 shorts 32768 B: W full-chunk dbuf -> relu f32 [16][256] -> V_dash f32
    //   sVT  bf16 [96][36]   6912 B: V^T (c-major), then V_h^T
    __shared__ __attribute__((aligned(16))) unsigned short sX[BN * SXS];
    __shared__ __attribute__((aligned(16))) unsigned short sWb[2 * 8192];
    __shared__ __attribute__((aligned(16))) unsigned short sVT[96 * VTS];

    const int t  = threadIdx.x;
    const int w  = t >> 6, l = t & 63;
    const int fr = l & 15, fq = l >> 4;
    const int n0 = blockIdx.x * BN;
    const int half = w & 1, oh = w >> 1;   // phase A/D wave mapping

    // ---------------- prologue: issue W chunk 0 (async, overlaps staging) ------
    if (USE_WS) {
        #pragma unroll
        for (int i = 0; i < 4; ++i)
            glds16(wpack + (w * 4 + i) * 512 + l * 8,
                   (char*)sWb + (w * 4 + i) * 1024);
    }

    // ---------------- stage s -> sX (bf16), V -> sVT (bf16, c-major transpose) --
    #pragma unroll
    for (int i = 0; i < 8; ++i) {
        int n = i * 4 + w;
        float4 x4 = *(const float4*)&s[(size_t)(n0 + n) * 256 + 4 * l];
        ushort4 h4; h4.x = f2b(x4.x); h4.y = f2b(x4.y); h4.z = f2b(x4.z); h4.w = f2b(x4.w);
        *(ushort4*)&sX[n * SXS + 4 * l] = h4;
    }
    #pragma unroll
    for (int i = 0; i < 3; ++i) {
        int f = i * NT + t;                      // 0..767 f4 slots
        float4 v4 = *(const float4*)&V[(size_t)n0 * 96 + f * 4];
        #pragma unroll
        for (int e = 0; e < 4; ++e) {
            int g = f * 4 + e;
            int n = g / 96, rem = g % 96, v = rem / 3, c = rem % 3;
            float val = (e == 0) ? v4.x : (e == 1) ? v4.y : (e == 2) ? v4.z : v4.w;
            sVT[(c * 32 + n) * VTS + v] = f2b(val);
        }
    }
    if (!USE_WS) {   // fallback: cvt-stage chunk 0
        const float* p = &Wmw[t * 288];
        #pragma unroll
        for (int j = 0; j < 4; ++j)
            *(bf16x8*)&sWb[t * 32 + ((j ^ ((t >> 1) & 3)) << 3)] = cvt8(p + j * 8);
    }
    __syncthreads();   // staging + chunk 0 visible (barrier drains vmcnt)

    // ---------------- phase A: V_h = Wh@V via MFMA; s_h -> sX[.,256..] ---------
    {
        bf16x8 bh = cvt8(&Wh[(oh * 16 + fr) * 32 + fq * 8]);   // dense L1 read
        f32x4 va0 = {0,0,0,0}, va1 = {0,0,0,0}, va2 = {0,0,0,0};
        bf16x8 a0 = *(const bf16x8*)&sVT[(0 * 32 + half * 16 + fr) * VTS + fq * 8];
        bf16x8 a1 = *(const bf16x8*)&sVT[(1 * 32 + half * 16 + fr) * VTS + fq * 8];
        bf16x8 a2 = *(const bf16x8*)&sVT[(2 * 32 + half * 16 + fr) * VTS + fq * 8];
        va0 = __builtin_amdgcn_mfma_f32_16x16x32_bf16(a0, bh, va0, 0, 0, 0);
        va1 = __builtin_amdgcn_mfma_f32_16x16x32_bf16(a1, bh, va1, 0, 0, 0);
        va2 = __builtin_amdgcn_mfma_f32_16x16x32_bf16(a2, bh, va2, 0, 0, 0);
        __syncthreads();            // all V^T reads done -> sVT writable as V_h^T
        #pragma unroll
        for (int r = 0; r < 4; ++r) {
            int nl = half * 16 + fq * 4 + r;       // node within block
            int h  = oh * 16 + fr;
            sVT[(0 * 32 + nl) * VTS + h] = f2b(va0[r]);
            sVT[(1 * 32 + nl) * VTS + h] = f2b(va1[r]);
            sVT[(2 * 32 + nl) * VTS + h] = f2b(va2[r]);
            float nrm = sqrtf(fmaf(va0[r], va0[r], fmaf(va1[r], va1[r], va2[r] * va2[r])));
            sX[nl * SXS + 256 + h] = f2b(fmaxf(nrm, 1e-4f));
        }
    }
    __syncthreads();                // V_h^T + s_h visible to all waves

    // ---------------- main GEMM: s_m = [s|s_h] @ Wmw^T (r2-exact structure) ----
    f32x4 acc[2][4];
    #pragma unroll
    for (int mt = 0; mt < 2; ++mt)
        #pragma unroll
        for (int j = 0; j < 4; ++j) acc[mt][j] = (f32x4){0.f, 0.f, 0.f, 0.f};

    #pragma unroll
    for (int ks = 0; ks < 9; ++ks) {
        unsigned short* bw = sWb + (ks & 1) * 8192;
        if (USE_WS) {
            if (ks < 8) {       // issue next full chunk into the other buffer
                #pragma unroll
                for (int i = 0; i < 4; ++i)
                    glds16(wpack + (ks + 1) * 8192 + (w * 4 + i) * 512 + l * 8,
                           (char*)sWb + ((ks + 1) & 1) * 16384 + (w * 4 + i) * 1024);
            }
        } else {
            bw = sWb;
            if (ks > 0) {
                __syncthreads();
                const float* p = &Wmw[t * 288 + ks * 32];
                #pragma unroll
                for (int j = 0; j < 4; ++j)
                    *(bf16x8*)&sWb[t * 32 + ((j ^ ((t >> 1) & 3)) << 3)] = cvt8(p + j * 8);
                __syncthreads();
            }
        }
        bf16x8 a0 = *(const bf16x8*)&sX[fr * SXS + ks * 32 + fq * 8];
        bf16x8 a1 = *(const bf16x8*)&sX[(16 + fr) * SXS + ks * 32 + fq * 8];
        bf16x8 b[4];
        #pragma unroll
        for (int j = 0; j < 4; ++j) {
            int o = w * 64 + j * 16 + fr;
            b[j] = *(const bf16x8*)&bw[o * 32 + ((fq * 8) ^ (((o >> 1) & 3) << 3))];
        }
        #pragma unroll
        for (int j = 0; j < 4; ++j) {
            acc[0][j] = __builtin_amdgcn_mfma_f32_16x16x32_bf16(a0, b[j], acc[0][j], 0, 0, 0);
            acc[1][j] = __builtin_amdgcn_mfma_f32_16x16x32_bf16(a1, b[j], acc[1][j], 0, 0, 0);
        }
        if (USE_WS) __syncthreads();
    }
    if (!USE_WS) __syncthreads();

    // ---------------- epilogue: sigmoid -> sX; relu restaged via sWb -----------
    float bias[4];
    #pragma unroll
    for (int j = 0; j < 4; ++j) bias[j] = Wmb[w * 64 + j * 16 + fr];

    float* sRel = (float*)sWb;  // [16][256] f32 per pass
    #pragma unroll
    for (int mt = 0; mt < 2; ++mt) {
        #pragma unroll
        for (int r = 0; r < 4; ++r) {
            int row  = fq * 4 + r;
            int node = mt * 16 + row;
            #pragma unroll
            for (int j = 0; j < 4; ++j) {
                int col = w * 64 + j * 16 + fr;
                float m = acc[mt][j][r] + bias[j];
                sX[node * SXS + col] = f2b(1.f / (1.f + __expf(-m)));
                sRel[row * 256 + col] = fmaxf(m, 0.f);
            }
        }
        __syncthreads();
        #pragma unroll
        for (int i = 0; i < 4; ++i) {
            int flat = i * NT + t;            // 1024 f4 slots = 16 rows x 64
            int row = flat >> 6, c4 = flat & 63;
            float4 v4 = *(const float4*)&sRel[row * 256 + c4 * 4];
            *(float4*)&out[(size_t)(n0 + mt * 16 + row) * 256 + c4 * 4] = v4;
        }
        __syncthreads();
    }

    // ---------------- gate GEMM; gate bf16 -> sX[.,256..] ----------------------
    {
        const int gmt = w & 1, gnt = w >> 1;
        f32x4 g = (f32x4){0.f, 0.f, 0.f, 0.f};
        #pragma unroll
        for (int ks = 0; ks < 8; ++ks) {
            bf16x8 a = *(const bf16x8*)&sX[(gmt * 16 + fr) * SXS + ks * 32 + fq * 8];
            bf16x8 b;
            if (USE_WS) b = *(const bf16x8*)&wpack[73728 + ks * 1024 + (gnt * 16 + fr) * 32 + fq * 8];
            else        b = cvt8(&Wgw[(gnt * 16 + fr) * 256 + ks * 32 + fq * 8]);
            g = __builtin_amdgcn_mfma_f32_16x16x32_bf16(a, b, g, 0, 0, 0);
        }
        int mo = gnt * 16 + fr;
        float gb = Wgb[mo];
        #pragma unroll
        for (int r = 0; r < 4; ++r) {
            int node = gmt * 16 + fq * 4 + r;
            sX[node * SXS + 256 + mo] = f2b(1.f / (1.f + __expf(-(g[r] + gb))));
        }
    }
    __syncthreads();            // gate visible; sWb dead -> f32 V_dash scratch

    // ---------------- phase D: V_mu = Wmu@V_h via MFMA; gate; store ------------
    float* sc = (float*)sWb;    // [32][96] f32 = 12288 B
    {
        bf16x8 bm = cvt8(&Wmu[(oh * 16 + fr) * 32 + fq * 8]);
        f32x4 m0 = {0,0,0,0}, m1 = {0,0,0,0}, m2 = {0,0,0,0};
        bf16x8 a0 = *(const bf16x8*)&sVT[(0 * 32 + half * 16 + fr) * VTS + fq * 8];
        bf16x8 a1 = *(const bf16x8*)&sVT[(1 * 32 + half * 16 + fr) * VTS + fq * 8];
        bf16x8 a2 = *(const bf16x8*)&sVT[(2 * 32 + half * 16 + fr) * VTS + fq * 8];
        m0 = __builtin_amdgcn_mfma_f32_16x16x32_bf16(a0, bm, m0, 0, 0, 0);
        m1 = __builtin_amdgcn_mfma_f32_16x16x32_bf16(a1, bm, m1, 0, 0, 0);
        m2 = __builtin_amdgcn_mfma_f32_16x16x32_bf16(a2, bm, m2, 0, 0, 0);
        #pragma unroll
        for (int r = 0; r < 4; ++r) {
            int node = half * 16 + fq * 4 + r;
            int m    = oh * 16 + fr;
            float g  = b2f(sX[node * SXS + 256 + m]);
            sc[node * 96 + m * 3 + 0] = g * m0[r];
            sc[node * 96 + m * 3 + 1] = g * m1[r];
            sc[node * 96 + m * 3 + 2] = g * m2[r];
        }
    }
    __syncthreads();
    const size_t VBASE = (size_t)NTOT * 256;
    #pragma unroll
    for (int i = 0; i < 3; ++i) {
        int f = i * NT + t;
        *(float4*)&out[VBASE + (size_t)n0 * 96 + f * 4] = *(const float4*)&sc[f * 4];
    }
}

extern "C" void kernel_launch(void* const* d_in, const int* in_sizes, int n_in,
                              void* d_out, int out_size, void* d_ws, size_t ws_size,
                              hipStream_t stream) {
    const float* s   = (const float*)d_in[0];
    const float* V   = (const float*)d_in[1];
    const float* Wh  = (const float*)d_in[2];
    const float* Wmu = (const float*)d_in[3];
    const float* Wmw = (const float*)d_in[4];
    const float* Wmb = (const float*)d_in[5];
    const float* Wgw = (const float*)d_in[6];
    const float* Wgb = (const float*)d_in[7];
    float* out = (float*)d_out;

    dim3 grid(NTOT / BN);   // 8192
    dim3 block(NT);         // 256

    if (ws_size >= 163840) {
        pack_w<<<320, 256, 0, stream>>>(Wmw, Wgw, (unsigned short*)d_ws);
        gvp_main<1><<<grid, block, 0, stream>>>(s, V, Wh, Wmu, Wmw, Wmb, Wgw, Wgb,
                                                (const unsigned short*)d_ws, out);
    } else {
        gvp_main<0><<<grid, block, 0, stream>>>(s, V, Wh, Wmu, Wmw, Wmb, Wgw, Wgb,
                                                nullptr, out);
    }
}

// Round 11
// 219.577 us; speedup vs baseline: 2.4973x; 1.1468x over previous
//
#include <hip/hip_runtime.h>

#define NTOT 262144
#define BN   32
#define NT   256
#define SXS  296     // sX row stride in shorts (288 + 8 pad; conflict-free b128 reads)
#define VTS  36      // V^T / V_h^T row stride in shorts (32 + 4 pad)

typedef __attribute__((ext_vector_type(8))) short bf16x8;
typedef __attribute__((ext_vector_type(4))) float f32x4;

static __device__ __forceinline__ unsigned short f2b(float x) {
    union { float f; unsigned u; } c; c.f = x;
    unsigned r = c.u + 0x7FFFu + ((c.u >> 16) & 1u);   // RNE
    return (unsigned short)(r >> 16);
}
static __device__ __forceinline__ float b2f(unsigned short h) {
    union { unsigned u; float f; } c; c.u = ((unsigned)h) << 16; return c.f;
}
static __device__ __forceinline__ bf16x8 cvt8(const float* p) {
    float4 x = *(const float4*)p, y = *(const float4*)(p + 4);
    bf16x8 r;
    r[0] = (short)f2b(x.x); r[1] = (short)f2b(x.y); r[2] = (short)f2b(x.z); r[3] = (short)f2b(x.w);
    r[4] = (short)f2b(y.x); r[5] = (short)f2b(y.y); r[6] = (short)f2b(y.z); r[7] = (short)f2b(y.w);
    return r;
}
static __device__ __forceinline__ void glds16(const unsigned short* g, void* l) {
    __builtin_amdgcn_global_load_lds(
        (const __attribute__((address_space(1))) void*)g,
        (__attribute__((address_space(3))) void*)l, 16, 0, 0);
}

// Pack W_m_w -> bf16, 18 half-chunks [128 cols][32 k] (it = ks*2 + ch),
// XOR-swizzled on k (kk ^= ((ol>>1)&3)<<3) -> conflict-free B-frag b128 reads.
// W_g_w -> bf16 k-chunked at offset 73728.
__global__ void pack_w(const float* __restrict__ Wmw, const float* __restrict__ Wgw,
                       unsigned short* __restrict__ wp) {
    int t = blockIdx.x * 256 + threadIdx.x;
    if (t < 73728) {
        int o = t / 288, k = t % 288;
        int ks = k >> 5, kk = k & 31, ch = o >> 7, ol = o & 127;
        int kks = kk ^ (((ol >> 1) & 3) << 3);
        wp[(ks * 2 + ch) * 4096 + ol * 32 + kks] = f2b(Wmw[t]);
    } else if (t < 81920) {
        int j = t - 73728;
        int o = j >> 8, k = j & 255;
        wp[73728 + (k >> 5) * 1024 + o * 32 + (k & 31)] = f2b(Wgw[j]);
    }
}

// Phases A (V_h = Wh@V, s_h) and D (V_mu = Wmu@V_h) are MFMA with c-major rows
// (row = c*32+n): 3 MFMAs/wave with the same (node, h/m) lane mapping across c.
// GEMM: 18 half-chunk iters, 16 KB dbuf, barrier/iter (r8-proven loop + swizzle).
// LDS 42,240 B -> 3 blocks/CU; launch_bounds(NT,3) (r7/r8: ~85 VGPR, no spill).
template<int USE_WS>
__global__ __launch_bounds__(NT, 3)
void gvp_main(const float* __restrict__ s, const float* __restrict__ V,
              const float* __restrict__ Wh, const float* __restrict__ Wmu,
              const float* __restrict__ Wmw, const float* __restrict__ Wmb,
              const float* __restrict__ Wgw, const float* __restrict__ Wgb,
              const unsigned short* __restrict__ wpack,
              float* __restrict__ out)
{
    // sX  bf16 [32][296] 18944 B: s | s_h -> sigmoid(s_m) | gate
    // sWb 2 x 4096 shorts 16384 B: W half-chunk dbuf -> relu f32 [16][256] -> V_dash f32
    // sVT bf16 [96][36]   6912 B: V^T (c-major), then V_h^T
    __shared__ __attribute__((aligned(16))) unsigned short sX[BN * SXS];
    __shared__ __attribute__((aligned(16))) unsigned short sWb[2 * 4096];
    __shared__ __attribute__((aligned(16))) unsigned short sVT[96 * VTS];

    const int t  = threadIdx.x;
    const int w  = t >> 6, l = t & 63;
    const int fr = l & 15, fq = l >> 4;
    const int n0 = blockIdx.x * BN;
    const int half = w & 1, oh = w >> 1;   // phase A/D wave mapping

    // ---------------- prologue: issue W half-chunk 0 (async) -------------------
    if (USE_WS) {
        const unsigned short* src = wpack + w * 1024 + l * 8;
        unsigned short* dst = sWb + w * 1024;
        glds16(src, dst);
        glds16(src + 512, dst + 512);
    }

    // ---------------- stage s -> sX (bf16), V -> sVT (c-major transpose) -------
    #pragma unroll
    for (int i = 0; i < 8; ++i) {
        int n = i * 4 + w;
        float4 x4 = *(const float4*)&s[(size_t)(n0 + n) * 256 + 4 * l];
        ushort4 h4; h4.x = f2b(x4.x); h4.y = f2b(x4.y); h4.z = f2b(x4.z); h4.w = f2b(x4.w);
        *(ushort4*)&sX[n * SXS + 4 * l] = h4;
    }
    {   // thread t -> node n = t>>3, v-quad vq = t&7: 48 consecutive bytes in,
        // three short4 LDS writes out (no div/mod, vectorized)
        int n = t >> 3, vq = t & 7;
        const float* p = &V[(size_t)(n0 + n) * 96 + vq * 12];
        float4 q0 = *(const float4*)(p);
        float4 q1 = *(const float4*)(p + 4);
        float4 q2 = *(const float4*)(p + 8);
        // q layout: v=4vq+dv, c: (0,0)(0,1)(0,2)(1,0) | (1,1)(1,2)(2,0)(2,1) | (2,2)(3,0)(3,1)(3,2)
        ushort4 c0 = { f2b(q0.x), f2b(q0.w), f2b(q1.z), f2b(q2.y) };   // c=0, dv=0..3
        ushort4 c1 = { f2b(q0.y), f2b(q1.x), f2b(q1.w), f2b(q2.z) };   // c=1
        ushort4 c2 = { f2b(q0.z), f2b(q1.y), f2b(q2.x), f2b(q2.w) };   // c=2
        *(ushort4*)&sVT[(0 * 32 + n) * VTS + vq * 4] = c0;
        *(ushort4*)&sVT[(1 * 32 + n) * VTS + vq * 4] = c1;
        *(ushort4*)&sVT[(2 * 32 + n) * VTS + vq * 4] = c2;
    }
    if (!USE_WS) {   // fallback: cvt-stage half-chunk 0 (it=0: ks=0, ch=0)
        int ol = w * 32 + (l >> 1), kh = l & 1, x = (ol >> 1) & 3;
        const float* p = &Wmw[ol * 288 + kh * 16];
        *(bf16x8*)&sWb[ol * 32 + (((kh * 2 + 0) ^ x) << 3)] = cvt8(p);
        *(bf16x8*)&sWb[ol * 32 + (((kh * 2 + 1) ^ x) << 3)] = cvt8(p + 8);
    }
    __syncthreads();   // staging + chunk 0 visible (barrier drains vmcnt)

    // ---------------- phase A: V_h = Wh@V via MFMA; s_h -> sX[.,256..] ---------
    {
        bf16x8 bh = cvt8(&Wh[(oh * 16 + fr) * 32 + fq * 8]);   // L1-hot
        f32x4 va0 = {0,0,0,0}, va1 = {0,0,0,0}, va2 = {0,0,0,0};
        bf16x8 a0 = *(const bf16x8*)&sVT[(0 * 32 + half * 16 + fr) * VTS + fq * 8];
        bf16x8 a1 = *(const bf16x8*)&sVT[(1 * 32 + half * 16 + fr) * VTS + fq * 8];
        bf16x8 a2 = *(const bf16x8*)&sVT[(2 * 32 + half * 16 + fr) * VTS + fq * 8];
        va0 = __builtin_amdgcn_mfma_f32_16x16x32_bf16(a0, bh, va0, 0, 0, 0);
        va1 = __builtin_amdgcn_mfma_f32_16x16x32_bf16(a1, bh, va1, 0, 0, 0);
        va2 = __builtin_amdgcn_mfma_f32_16x16x32_bf16(a2, bh, va2, 0, 0, 0);
        __syncthreads();            // V^T reads done -> sVT writable as V_h^T
        #pragma unroll
        for (int r = 0; r < 4; ++r) {
            int nl = half * 16 + fq * 4 + r;
            int h  = oh * 16 + fr;
            sVT[(0 * 32 + nl) * VTS + h] = f2b(va0[r]);
            sVT[(1 * 32 + nl) * VTS + h] = f2b(va1[r]);
            sVT[(2 * 32 + nl) * VTS + h] = f2b(va2[r]);
            float nrm = sqrtf(fmaf(va0[r], va0[r], fmaf(va1[r], va1[r], va2[r] * va2[r])));
            sX[nl * SXS + 256 + h] = f2b(fmaxf(nrm, 1e-4f));
        }
    }
    __syncthreads();                // V_h^T + s_h visible

    // ---------------- main GEMM: 18 half-chunk iters, dbuf glds, barrier/iter --
    // acc[mt][ji]: ji = ch*2 + jt -> col = ch*128 + w*32 + jt*16 + fr
    f32x4 acc[2][4];
    #pragma unroll
    for (int mt = 0; mt < 2; ++mt)
        #pragma unroll
        for (int j = 0; j < 4; ++j) acc[mt][j] = (f32x4){0.f, 0.f, 0.f, 0.f};

    const int ol0 = w * 32 + fr, ol1 = ol0 + 16;
    const int bo0 = ol0 * 32 + ((fq ^ ((ol0 >> 1) & 3)) << 3);
    const int bo1 = ol1 * 32 + ((fq ^ ((ol1 >> 1) & 3)) << 3);

    #pragma unroll
    for (int it = 0; it < 18; ++it) {
        if (it < 17) {          // stage next half-chunk into the other buffer
            if (USE_WS) {
                const unsigned short* src = wpack + (it + 1) * 4096 + w * 1024 + l * 8;
                unsigned short* dst = sWb + ((it + 1) & 1) * 4096 + w * 1024;
                glds16(src, dst);
                glds16(src + 512, dst + 512);
            } else {
                int it1 = it + 1, ks1 = it1 >> 1, ch1 = it1 & 1;
                int ol = w * 32 + (l >> 1), kh = l & 1, x = (ol >> 1) & 3;
                const float* p = &Wmw[(ch1 * 128 + ol) * 288 + ks1 * 32 + kh * 16];
                unsigned short* dst = sWb + (it1 & 1) * 4096;
                *(bf16x8*)&dst[ol * 32 + (((kh * 2 + 0) ^ x) << 3)] = cvt8(p);
                *(bf16x8*)&dst[ol * 32 + (((kh * 2 + 1) ^ x) << 3)] = cvt8(p + 8);
            }
        }
        const int ks = it >> 1;
        const unsigned short* bw = sWb + (it & 1) * 4096;
        bf16x8 a0 = *(const bf16x8*)&sX[fr * SXS + ks * 32 + fq * 8];
        bf16x8 a1 = *(const bf16x8*)&sX[(16 + fr) * SXS + ks * 32 + fq * 8];
        bf16x8 b0 = *(const bf16x8*)&bw[bo0];
        bf16x8 b1 = *(const bf16x8*)&bw[bo1];
        const int ji = (it & 1) * 2;   // static under full unroll
        acc[0][ji + 0] = __builtin_amdgcn_mfma_f32_16x16x32_bf16(a0, b0, acc[0][ji + 0], 0, 0, 0);
        acc[1][ji + 0] = __builtin_amdgcn_mfma_f32_16x16x32_bf16(a1, b0, acc[1][ji + 0], 0, 0, 0);
        acc[0][ji + 1] = __builtin_amdgcn_mfma_f32_16x16x32_bf16(a0, b1, acc[0][ji + 1], 0, 0, 0);
        acc[1][ji + 1] = __builtin_amdgcn_mfma_f32_16x16x32_bf16(a1, b1, acc[1][ji + 1], 0, 0, 0);
        __syncthreads();        // buffer swap; drains glds for it+1
    }

    // ---------------- epilogue: sigmoid -> sX; relu restaged via sWb -----------
    float bias[4];
    #pragma unroll
    for (int ji = 0; ji < 4; ++ji)
        bias[ji] = Wmb[(ji >> 1) * 128 + w * 32 + (ji & 1) * 16 + fr];

    float* sRel = (float*)sWb;  // [16][256] f32 per pass (16384 B = sWb exactly)
    #pragma unroll
    for (int mt = 0; mt < 2; ++mt) {
        #pragma unroll
        for (int r = 0; r < 4; ++r) {
            int row  = fq * 4 + r;
            int node = mt * 16 + row;
            #pragma unroll
            for (int ji = 0; ji < 4; ++ji) {
                int col = (ji >> 1) * 128 + w * 32 + (ji & 1) * 16 + fr;
                float m = acc[mt][ji][r] + bias[ji];
                sX[node * SXS + col] = f2b(1.f / (1.f + __expf(-m)));
                sRel[row * 256 + col] = fmaxf(m, 0.f);
            }
        }
        __syncthreads();
        #pragma unroll
        for (int i = 0; i < 4; ++i) {
            int flat = i * NT + t;            // 1024 f4 slots = 16 rows x 64
            int row = flat >> 6, c4 = flat & 63;
            float4 v4 = *(const float4*)&sRel[row * 256 + c4 * 4];
            *(float4*)&out[(size_t)(n0 + mt * 16 + row) * 256 + c4 * 4] = v4;
        }
        __syncthreads();
    }

    // ---------------- gate GEMM; gate bf16 -> sX[.,256..] ----------------------
    {
        const int gmt = w & 1, gnt = w >> 1;
        f32x4 g = (f32x4){0.f, 0.f, 0.f, 0.f};
        #pragma unroll
        for (int ks = 0; ks < 8; ++ks) {
            bf16x8 a = *(const bf16x8*)&sX[(gmt * 16 + fr) * SXS + ks * 32 + fq * 8];
            bf16x8 b;
            if (USE_WS) b = *(const bf16x8*)&wpack[73728 + ks * 1024 + (gnt * 16 + fr) * 32 + fq * 8];
            else        b = cvt8(&Wgw[(gnt * 16 + fr) * 256 + ks * 32 + fq * 8]);
            g = __builtin_amdgcn_mfma_f32_16x16x32_bf16(a, b, g, 0, 0, 0);
        }
        int mo = gnt * 16 + fr;
        float gb = Wgb[mo];
        #pragma unroll
        for (int r = 0; r < 4; ++r) {
            int node = gmt * 16 + fq * 4 + r;
            sX[node * SXS + 256 + mo] = f2b(1.f / (1.f + __expf(-(g[r] + gb))));
        }
    }
    __syncthreads();            // gate visible; sWb dead -> f32 V_dash scratch

    // ---------------- phase D: V_mu = Wmu@V_h via MFMA; gate; store ------------
    float* sc = (float*)sWb;    // [32][96] f32 = 12288 B <= 16384 B
    {
        bf16x8 bm = cvt8(&Wmu[(oh * 16 + fr) * 32 + fq * 8]);
        f32x4 m0 = {0,0,0,0}, m1 = {0,0,0,0}, m2 = {0,0,0,0};
        bf16x8 a0 = *(const bf16x8*)&sVT[(0 * 32 + half * 16 + fr) * VTS + fq * 8];
        bf16x8 a1 = *(const bf16x8*)&sVT[(1 * 32 + half * 16 + fr) * VTS + fq * 8];
        bf16x8 a2 = *(const bf16x8*)&sVT[(2 * 32 + half * 16 + fr) * VTS + fq * 8];
        m0 = __builtin_amdgcn_mfma_f32_16x16x32_bf16(a0, bm, m0, 0, 0, 0);
        m1 = __builtin_amdgcn_mfma_f32_16x16x32_bf16(a1, bm, m1, 0, 0, 0);
        m2 = __builtin_amdgcn_mfma_f32_16x16x32_bf16(a2, bm, m2, 0, 0, 0);
        #pragma unroll
        for (int r = 0; r < 4; ++r) {
            int node = half * 16 + fq * 4 + r;
            int m    = oh * 16 + fr;
            float g  = b2f(sX[node * SXS + 256 + m]);
            sc[node * 96 + m * 3 + 0] = g * m0[r];
            sc[node * 96 + m * 3 + 1] = g * m1[r];
            sc[node * 96 + m * 3 + 2] = g * m2[r];
        }
    }
    __syncthreads();
    const size_t VBASE = (size_t)NTOT * 256;
    #pragma unroll
    for (int i = 0; i < 3; ++i) {
        int f = i * NT + t;
        *(float4*)&out[VBASE + (size_t)n0 * 96 + f * 4] = *(const float4*)&sc[f * 4];
    }
}

extern "C" void kernel_launch(void* const* d_in, const int* in_sizes, int n_in,
                              void* d_out, int out_size, void* d_ws, size_t ws_size,
                              hipStream_t stream) {
    const float* s   = (const float*)d_in[0];
    const float* V   = (const float*)d_in[1];
    const float* Wh  = (const float*)d_in[2];
    const float* Wmu = (const float*)d_in[3];
    const float* Wmw = (const float*)d_in[4];
    const float* Wmb = (const float*)d_in[5];
    const float* Wgw = (const float*)d_in[6];
    const float* Wgb = (const float*)d_in[7];
    float* out = (float*)d_out;

    dim3 grid(NTOT / BN);   // 8192
    dim3 block(NT);         // 256

    if (ws_size >= 163840) {
        pack_w<<<320, 256, 0, stream>>>(Wmw, Wgw, (unsigned short*)d_ws);
        gvp_main<1><<<grid, block, 0, stream>>>(s, V, Wh, Wmu, Wmw, Wmb, Wgw, Wgb,
                                                (const unsigned short*)d_ws, out);
    } else {
        gvp_main<0><<<grid, block, 0, stream>>>(s, V, Wh, Wmu, Wmw, Wmb, Wgw, Wgb,
                                                nullptr, out);
    }
}

// Round 12
// 208.337 us; speedup vs baseline: 2.6321x; 1.0540x over previous
//
#include <hip/hip_runtime.h>

#define NTOT 262144
#define BN   32
#define NT   256
#define SXS  296     // sX row stride in shorts (288 + 8 pad; conflict-free b128 reads)
#define VTS  36      // V^T / V_h^T row stride in shorts (32 + 4 pad)

typedef __attribute__((ext_vector_type(8))) short bf16x8;
typedef __attribute__((ext_vector_type(4))) float f32x4;

static __device__ __forceinline__ unsigned short f2b(float x) {
    union { float f; unsigned u; } c; c.f = x;
    unsigned r = c.u + 0x7FFFu + ((c.u >> 16) & 1u);   // RNE
    return (unsigned short)(r >> 16);
}
static __device__ __forceinline__ float b2f(unsigned short h) {
    union { unsigned u; float f; } c; c.u = ((unsigned)h) << 16; return c.f;
}
static __device__ __forceinline__ bf16x8 cvt8(const float* p) {
    float4 x = *(const float4*)p, y = *(const float4*)(p + 4);
    bf16x8 r;
    r[0] = (short)f2b(x.x); r[1] = (short)f2b(x.y); r[2] = (short)f2b(x.z); r[3] = (short)f2b(x.w);
    r[4] = (short)f2b(y.x); r[5] = (short)f2b(y.y); r[6] = (short)f2b(y.z); r[7] = (short)f2b(y.w);
    return r;
}
static __device__ __forceinline__ void glds16(const unsigned short* g, void* l) {
    __builtin_amdgcn_global_load_lds(
        (const __attribute__((address_space(1))) void*)g,
        (__attribute__((address_space(3))) void*)l, 16, 0, 0);
}

// Pack W_m_w -> bf16, 18 half-chunks [128 cols][32 k] (it = ks*2 + ch),
// XOR-swizzled on k (kk ^= ((ol>>1)&3)<<3) -> conflict-free B-frag b128 reads.
// W_g_w -> bf16 k-chunked at offset 73728.
__global__ void pack_w(const float* __restrict__ Wmw, const float* __restrict__ Wgw,
                       unsigned short* __restrict__ wp) {
    int t = blockIdx.x * 256 + threadIdx.x;
    if (t < 73728) {
        int o = t / 288, k = t % 288;
        int ks = k >> 5, kk = k & 31, ch = o >> 7, ol = o & 127;
        int kks = kk ^ (((ol >> 1) & 3) << 3);
        wp[(ks * 2 + ch) * 4096 + ol * 32 + kks] = f2b(Wmw[t]);
    } else if (t < 81920) {
        int j = t - 73728;
        int o = j >> 8, k = j & 255;
        wp[73728 + (k >> 5) * 1024 + o * 32 + (k & 31)] = f2b(Wgw[j]);
    }
}

// K-loop is BARRIER-FREE: each wave stages and reads ONLY its own 2 KB W slice
// (cols [32w,32w+32)), so no cross-wave hazard exists. Counted vmcnt(2) keeps
// the next chunk's glds in flight (never drained mid-loop); lgkmcnt(0)+
// sched_barrier guards each dbuf-slot overwrite (same-wave RAW).
template<int USE_WS>
__global__ __launch_bounds__(NT, 3)
void gvp_main(const float* __restrict__ s, const float* __restrict__ V,
              const float* __restrict__ Wh, const float* __restrict__ Wmu,
              const float* __restrict__ Wmw, const float* __restrict__ Wmb,
              const float* __restrict__ Wgw, const float* __restrict__ Wgb,
              const unsigned short* __restrict__ wpack,
              float* __restrict__ out)
{
    // sX  bf16 [32][296] 18944 B: s | s_h -> sigmoid(s_m) | gate
    // sWb 2 x 4096 shorts 16384 B: W half-chunk dbuf -> relu f32 [16][256] -> V_dash f32
    // sVT bf16 [96][36]   6912 B: V^T (c-major), then V_h^T    (total 42,240 B)
    __shared__ __attribute__((aligned(16))) unsigned short sX[BN * SXS];
    __shared__ __attribute__((aligned(16))) unsigned short sWb[2 * 4096];
    __shared__ __attribute__((aligned(16))) unsigned short sVT[96 * VTS];

    const int t  = threadIdx.x;
    const int w  = t >> 6, l = t & 63;
    const int fr = l & 15, fq = l >> 4;
    const int n0 = blockIdx.x * BN;
    const int half = w & 1, oh = w >> 1;   // phase A/D wave mapping

    // ---------------- prologue: issue W half-chunks 0,1 (async) ----------------
    if (USE_WS) {
        #pragma unroll
        for (int c = 0; c < 2; ++c) {
            const unsigned short* src = wpack + c * 4096 + w * 1024 + l * 8;
            unsigned short* dst = sWb + c * 4096 + w * 1024;
            glds16(src, dst);
            glds16(src + 512, dst + 512);
        }
    }

    // ---------------- stage s -> sX (bf16), V -> sVT (c-major transpose) -------
    #pragma unroll
    for (int i = 0; i < 8; ++i) {
        int n = i * 4 + w;
        float4 x4 = *(const float4*)&s[(size_t)(n0 + n) * 256 + 4 * l];
        ushort4 h4; h4.x = f2b(x4.x); h4.y = f2b(x4.y); h4.z = f2b(x4.z); h4.w = f2b(x4.w);
        *(ushort4*)&sX[n * SXS + 4 * l] = h4;
    }
    {   // thread t -> node n = t>>3, v-quad vq = t&7: 48 consecutive bytes in,
        // three short4 LDS writes out (no div/mod, vectorized)
        int n = t >> 3, vq = t & 7;
        const float* p = &V[(size_t)(n0 + n) * 96 + vq * 12];
        float4 q0 = *(const float4*)(p);
        float4 q1 = *(const float4*)(p + 4);
        float4 q2 = *(const float4*)(p + 8);
        ushort4 c0 = { f2b(q0.x), f2b(q0.w), f2b(q1.z), f2b(q2.y) };   // c=0, dv=0..3
        ushort4 c1 = { f2b(q0.y), f2b(q1.x), f2b(q1.w), f2b(q2.z) };   // c=1
        ushort4 c2 = { f2b(q0.z), f2b(q1.y), f2b(q2.x), f2b(q2.w) };   // c=2
        *(ushort4*)&sVT[(0 * 32 + n) * VTS + vq * 4] = c0;
        *(ushort4*)&sVT[(1 * 32 + n) * VTS + vq * 4] = c1;
        *(ushort4*)&sVT[(2 * 32 + n) * VTS + vq * 4] = c2;
    }
    if (!USE_WS) {   // fallback: cvt-stage half-chunks 0,1
        #pragma unroll
        for (int c = 0; c < 2; ++c) {
            int ol = w * 32 + (l >> 1), kh = l & 1, x = (ol >> 1) & 3;
            const float* p = &Wmw[(c * 128 + ol) * 288 + kh * 16];
            unsigned short* dst = sWb + c * 4096;
            *(bf16x8*)&dst[ol * 32 + (((kh * 2 + 0) ^ x) << 3)] = cvt8(p);
            *(bf16x8*)&dst[ol * 32 + (((kh * 2 + 1) ^ x) << 3)] = cvt8(p + 8);
        }
    }
    __syncthreads();   // staging + chunks 0,1 visible (this barrier drains vmcnt)

    // ---------------- phase A: V_h = Wh@V via MFMA; s_h -> sX[.,256..] ---------
    {
        bf16x8 bh = cvt8(&Wh[(oh * 16 + fr) * 32 + fq * 8]);   // L1-hot
        f32x4 va0 = {0,0,0,0}, va1 = {0,0,0,0}, va2 = {0,0,0,0};
        bf16x8 a0 = *(const bf16x8*)&sVT[(0 * 32 + half * 16 + fr) * VTS + fq * 8];
        bf16x8 a1 = *(const bf16x8*)&sVT[(1 * 32 + half * 16 + fr) * VTS + fq * 8];
        bf16x8 a2 = *(const bf16x8*)&sVT[(2 * 32 + half * 16 + fr) * VTS + fq * 8];
        va0 = __builtin_amdgcn_mfma_f32_16x16x32_bf16(a0, bh, va0, 0, 0, 0);
        va1 = __builtin_amdgcn_mfma_f32_16x16x32_bf16(a1, bh, va1, 0, 0, 0);
        va2 = __builtin_amdgcn_mfma_f32_16x16x32_bf16(a2, bh, va2, 0, 0, 0);
        __syncthreads();            // V^T reads done -> sVT writable as V_h^T
        #pragma unroll
        for (int r = 0; r < 4; ++r) {
            int nl = half * 16 + fq * 4 + r;
            int h  = oh * 16 + fr;
            sVT[(0 * 32 + nl) * VTS + h] = f2b(va0[r]);
            sVT[(1 * 32 + nl) * VTS + h] = f2b(va1[r]);
            sVT[(2 * 32 + nl) * VTS + h] = f2b(va2[r]);
            float nrm = sqrtf(fmaf(va0[r], va0[r], fmaf(va1[r], va1[r], va2[r] * va2[r])));
            sX[nl * SXS + 256 + h] = f2b(fmaxf(nrm, 1e-4f));
        }
    }
    __syncthreads();                // V_h^T + s_h visible

    // ---------------- main GEMM: 18 iters, ZERO barriers, counted vmcnt --------
    f32x4 acc[2][4];
    #pragma unroll
    for (int mt = 0; mt < 2; ++mt)
        #pragma unroll
        for (int j = 0; j < 4; ++j) acc[mt][j] = (f32x4){0.f, 0.f, 0.f, 0.f};

    const int ol0 = w * 32 + fr, ol1 = ol0 + 16;
    const int bo0 = ol0 * 32 + ((fq ^ ((ol0 >> 1) & 3)) << 3);
    const int bo1 = ol1 * 32 + ((fq ^ ((ol1 >> 1) & 3)) << 3);

    #pragma unroll
    for (int it = 0; it < 18; ++it) {
        if (it >= 2) {          // chunk it's glds landed (per-wave FIFO count)
            if (it <= 16) asm volatile("s_waitcnt vmcnt(2)" ::: "memory");
            else          asm volatile("s_waitcnt vmcnt(0)" ::: "memory");
            __builtin_amdgcn_sched_barrier(0);
        }
        const int ks = it >> 1;
        const unsigned short* bw = sWb + (it & 1) * 4096;
        bf16x8 a0 = *(const bf16x8*)&sX[fr * SXS + ks * 32 + fq * 8];
        bf16x8 a1 = *(const bf16x8*)&sX[(16 + fr) * SXS + ks * 32 + fq * 8];
        bf16x8 b0 = *(const bf16x8*)&bw[bo0];
        bf16x8 b1 = *(const bf16x8*)&bw[bo1];
        if (it < 16) {          // refill this slot with chunk it+2 (wave-private)
            asm volatile("s_waitcnt lgkmcnt(0)" ::: "memory");   // slot reads retired
            __builtin_amdgcn_sched_barrier(0);
            if (USE_WS) {
                const unsigned short* src = wpack + (it + 2) * 4096 + w * 1024 + l * 8;
                unsigned short* dst = sWb + (it & 1) * 4096 + w * 1024;
                glds16(src, dst);
                glds16(src + 512, dst + 512);
            } else {
                int it2 = it + 2, ks2 = it2 >> 1, ch2 = it2 & 1;
                int ol = w * 32 + (l >> 1), kh = l & 1, x = (ol >> 1) & 3;
                const float* p = &Wmw[(ch2 * 128 + ol) * 288 + ks2 * 32 + kh * 16];
                unsigned short* dst = sWb + (it & 1) * 4096;
                *(bf16x8*)&dst[ol * 32 + (((kh * 2 + 0) ^ x) << 3)] = cvt8(p);
                *(bf16x8*)&dst[ol * 32 + (((kh * 2 + 1) ^ x) << 3)] = cvt8(p + 8);
            }
        }
        const int ji = (it & 1) * 2;   // static under full unroll
        acc[0][ji + 0] = __builtin_amdgcn_mfma_f32_16x16x32_bf16(a0, b0, acc[0][ji + 0], 0, 0, 0);
        acc[1][ji + 0] = __builtin_amdgcn_mfma_f32_16x16x32_bf16(a1, b0, acc[1][ji + 0], 0, 0, 0);
        acc[0][ji + 1] = __builtin_amdgcn_mfma_f32_16x16x32_bf16(a0, b1, acc[0][ji + 1], 0, 0, 0);
        acc[1][ji + 1] = __builtin_amdgcn_mfma_f32_16x16x32_bf16(a1, b1, acc[1][ji + 1], 0, 0, 0);
    }
    __syncthreads();            // all A-frag reads done -> sX writable

    // ---------------- epilogue: sigmoid -> sX; relu restaged via sWb (skewed) --
    float bias[4];
    #pragma unroll
    for (int ji = 0; ji < 4; ++ji)
        bias[ji] = Wmb[(ji >> 1) * 128 + w * 32 + (ji & 1) * 16 + fr];

    // bank skew: col ^ sk, sk = {0,16,8,24}[fq] -> fq groups split across bank
    // halves (2-way instead of 4-way). Bijective, float4-aligned, read-back aware.
    const int skw = ((fq & 1) << 4) | ((fq >> 1) << 3);
    float* sRel = (float*)sWb;  // [16][256] f32 per pass (16384 B = sWb exactly)
    #pragma unroll
    for (int mt = 0; mt < 2; ++mt) {
        #pragma unroll
        for (int r = 0; r < 4; ++r) {
            int row  = fq * 4 + r;
            int node = mt * 16 + row;
            #pragma unroll
            for (int ji = 0; ji < 4; ++ji) {
                int col = (ji >> 1) * 128 + w * 32 + (ji & 1) * 16 + fr;
                float m = acc[mt][ji][r] + bias[ji];
                sX[node * SXS + col] = f2b(1.f / (1.f + __expf(-m)));
                sRel[row * 256 + (col ^ skw)] = fmaxf(m, 0.f);
            }
        }
        __syncthreads();
        #pragma unroll
        for (int i = 0; i < 4; ++i) {
            int flat = i * NT + t;            // 1024 f4 slots = 16 rows x 64
            int row = flat >> 6, c4 = flat & 63;
            int sk2 = (((row >> 2) & 1) << 4) | (((row >> 3) & 1) << 3);
            float4 v4 = *(const float4*)&sRel[row * 256 + ((c4 * 4) ^ sk2)];
            *(float4*)&out[(size_t)(n0 + mt * 16 + row) * 256 + c4 * 4] = v4;
        }
        __syncthreads();
    }

    // ---------------- gate GEMM; gate bf16 -> sX[.,256..] ----------------------
    {
        const int gmt = w & 1, gnt = w >> 1;
        f32x4 g = (f32x4){0.f, 0.f, 0.f, 0.f};
        #pragma unroll
        for (int ks = 0; ks < 8; ++ks) {
            bf16x8 a = *(const bf16x8*)&sX[(gmt * 16 + fr) * SXS + ks * 32 + fq * 8];
            bf16x8 b;
            if (USE_WS) b = *(const bf16x8*)&wpack[73728 + ks * 1024 + (gnt * 16 + fr) * 32 + fq * 8];
            else        b = cvt8(&Wgw[(gnt * 16 + fr) * 256 + ks * 32 + fq * 8]);
            g = __builtin_amdgcn_mfma_f32_16x16x32_bf16(a, b, g, 0, 0, 0);
        }
        int mo = gnt * 16 + fr;
        float gb = Wgb[mo];
        #pragma unroll
        for (int r = 0; r < 4; ++r) {
            int node = gmt * 16 + fq * 4 + r;
            sX[node * SXS + 256 + mo] = f2b(1.f / (1.f + __expf(-(g[r] + gb))));
        }
    }
    __syncthreads();            // gate visible; sWb dead -> f32 V_dash scratch

    // ---------------- phase D: V_mu = Wmu@V_h via MFMA; gate; store ------------
    float* sc = (float*)sWb;    // [32][96] f32 = 12288 B <= 16384 B
    {
        bf16x8 bm = cvt8(&Wmu[(oh * 16 + fr) * 32 + fq * 8]);
        f32x4 m0 = {0,0,0,0}, m1 = {0,0,0,0}, m2 = {0,0,0,0};
        bf16x8 a0 = *(const bf16x8*)&sVT[(0 * 32 + half * 16 + fr) * VTS + fq * 8];
        bf16x8 a1 = *(const bf16x8*)&sVT[(1 * 32 + half * 16 + fr) * VTS + fq * 8];
        bf16x8 a2 = *(const bf16x8*)&sVT[(2 * 32 + half * 16 + fr) * VTS + fq * 8];
        m0 = __builtin_amdgcn_mfma_f32_16x16x32_bf16(a0, bm, m0, 0, 0, 0);
        m1 = __builtin_amdgcn_mfma_f32_16x16x32_bf16(a1, bm, m1, 0, 0, 0);
        m2 = __builtin_amdgcn_mfma_f32_16x16x32_bf16(a2, bm, m2, 0, 0, 0);
        #pragma unroll
        for (int r = 0; r < 4; ++r) {
            int node = half * 16 + fq * 4 + r;
            int m    = oh * 16 + fr;
            float g  = b2f(sX[node * SXS + 256 + m]);
            sc[node * 96 + m * 3 + 0] = g * m0[r];
            sc[node * 96 + m * 3 + 1] = g * m1[r];
            sc[node * 96 + m * 3 + 2] = g * m2[r];
        }
    }
    __syncthreads();
    const size_t VBASE = (size_t)NTOT * 256;
    #pragma unroll
    for (int i = 0; i < 3; ++i) {
        int f = i * NT + t;
        *(float4*)&out[VBASE + (size_t)n0 * 96 + f * 4] = *(const float4*)&sc[f * 4];
    }
}

extern "C" void kernel_launch(void* const* d_in, const int* in_sizes, int n_in,
                              void* d_out, int out_size, void* d_ws, size_t ws_size,
                              hipStream_t stream) {
    const float* s   = (const float*)d_in[0];
    const float* V   = (const float*)d_in[1];
    const float* Wh  = (const float*)d_in[2];
    const float* Wmu = (const float*)d_in[3];
    const float* Wmw = (const float*)d_in[4];
    const float* Wmb = (const float*)d_in[5];
    const float* Wgw = (const float*)d_in[6];
    const float* Wgb = (const float*)d_in[7];
    float* out = (float*)d_out;

    dim3 grid(NTOT / BN);   // 8192
    dim3 block(NT);         // 256

    if (ws_size >= 163840) {
        pack_w<<<320, 256, 0, stream>>>(Wmw, Wgw, (unsigned short*)d_ws);
        gvp_main<1><<<grid, block, 0, stream>>>(s, V, Wh, Wmu, Wmw, Wmb, Wgw, Wgb,
                                                (const unsigned short*)d_ws, out);
    } else {
        gvp_main<0><<<grid, block, 0, stream>>>(s, V, Wh, Wmu, Wmw, Wmb, Wgw, Wgb,
                                                nullptr, out);
    }
}